// Round 1
// baseline (145.795 us; speedup 1.0000x reference)
//
#include <hip/hip_runtime.h>

typedef _Float16 f16;
typedef _Float16 f16x8 __attribute__((ext_vector_type(8)));
typedef float f32x4 __attribute__((ext_vector_type(4)));

// ---------------- d_ws layout ----------------
// [0, 262144)        : f16 weight images, transposed [out_ch][in_ch], pre-swizzled
//   img i in 0..6  (L1..L7h, 128x128) at i*32768
//   img 7 (C0h 64x128) at 229376 (16384 B)
//   img 8 (C1 64x64)   at 245760 (8192 B)
//   img 9 (C2 64x64)   at 253952 (8192 B)
// [262144, +10240)   : fp32 params block (folded biases etc.)
#define WS_PARAMS 262144

// ---------------- LDS layout (bytes) ----------------
// act   [0, 65536)        : 256 pts x 128 ch f16, row stride 256B, swizzled
// Wbuf0 [65536, 98304)
// Wbuf1 [98304, 131072)
// params[131072, 141312)  : 2560 floats
// pos   [141312, 144384)  : 256 x 3 f32
// view  [144384, 144408)  : 2 x 3 f32
// sigma [144408, 145432)  : 256 f32
#define LDS_ACT   0
#define LDS_W0    65536
#define LDS_W1    98304
#define LDS_PRM   131072
#define LDS_POS   141312
#define LDS_VIEW  144384
#define LDS_SIG   144408
#define LDS_SIZE  145440

__device__ __forceinline__ int swz(int row, int byteInRow) {
  return byteInRow ^ ((row & 7) << 4);
}

struct Ptrs { const float* p[29]; };

// ---------------------------------------------------------------------------
// Prepass: fold cond into biases, convert/transpose/pre-swizzle weights to f16
// ---------------------------------------------------------------------------
__global__ void nerf_prep(Ptrs ptrs, char* __restrict__ ws) {
  const int t = threadIdx.x;
  if (blockIdx.x == 0) {
    float* P = (float*)(ws + WS_PARAMS);
    const float* cond = ptrs.p[1];
    const float* dW0 = ptrs.p[3];  const float* db0 = ptrs.p[4];
    const float* dW5 = ptrs.p[13]; const float* db5 = ptrs.p[14];
    if (t < 128) {
      float a0 = db0[t], a5 = db5[t];
      for (int k = 0; k < 64; ++k) {
        const float c = cond[k];
        a0 += c * dW0[(3 + k) * 128 + t];
        a5 += c * dW5[(3 + k) * 128 + t];
      }
      P[t] = a0;          // b0f
      P[512 + t] = a5;    // b5f
      for (int k = 0; k < 3; ++k) {
        P[128 + k * 128 + t] = dW0[k * 128 + t];   // W0p
        P[640 + k * 128 + t] = dW5[k * 128 + t];   // W5p
      }
      P[1024 + t] = ptrs.p[6][t];    // db1
      P[1152 + t] = ptrs.p[8][t];    // db2
      P[1280 + t] = ptrs.p[10][t];   // db3
      P[1408 + t] = ptrs.p[12][t];   // db4
      P[1536 + t] = ptrs.p[16][t];   // db6
      P[1664 + t] = ptrs.p[18][t];   // db7
      P[2176 + t] = ptrs.p[19][t];   // sW
    }
    if (t < 64) {
      P[1792 + t] = ptrs.p[22][t];   // cb0
      for (int k = 0; k < 3; ++k)    // cWv = cW0 rows 128..130
        P[1856 + k * 64 + t] = ptrs.p[21][(128 + k) * 64 + t];
      P[2048 + t] = ptrs.p[24][t];   // cb1
      P[2112 + t] = ptrs.p[26][t];   // cb2
    }
    if (t < 192) P[2305 + t] = ptrs.p[27][t];  // rW [64][3]
    if (t == 0) {
      P[2304] = ptrs.p[20][0];                 // sb
      P[2497] = ptrs.p[28][0];
      P[2498] = ptrs.p[28][1];
      P[2499] = ptrs.p[28][2];                 // rb
    }
    return;
  }
  // weight conversion: 131072 f16 elements across blocks 1..512
  const int w = (blockIdx.x - 1) * 256 + t;
  float v; int dst;
  if (w < 114688) {                       // L1..L7h: 7 images of 128x128
    const int img = w >> 14, r = w & 16383, n = r >> 7, k = r & 127;
    const int srow = k + (img == 4 ? 67 : 0);     // L5h uses dW5 rows 67..194
    v = ptrs.p[5 + 2 * img][srow * 128 + n];
    dst = img * 32768 + n * 256 + swz(n, 2 * k);
  } else if (w < 122880) {                // C0h: cW0 rows 0..127, N=64
    const int r = w - 114688, n = r >> 7, k = r & 127;
    v = ptrs.p[21][k * 64 + n];
    dst = 229376 + n * 256 + swz(n, 2 * k);
  } else if (w < 126976) {                // C1 64x64
    const int r = w - 122880, n = r >> 6, k = r & 63;
    v = ptrs.p[23][k * 64 + n];
    dst = 245760 + n * 128 + swz(n, 2 * k);
  } else {                                // C2 64x64
    const int r = w - 126976, n = r >> 6, k = r & 63;
    v = ptrs.p[25][k * 64 + n];
    dst = 253952 + n * 128 + swz(n, 2 * k);
  }
  *(f16*)(ws + dst) = (f16)v;
}

// ---------------------------------------------------------------------------
// Main fused kernel
// ---------------------------------------------------------------------------
__device__ __forceinline__ void stage(const char* __restrict__ g, char* d,
                                      int bytes, int t) {
  for (int off = t * 16; off < bytes; off += 8192)
    *(int4*)(d + off) = *(const int4*)(g + off);
}

// INIT: 0 = bias only, 1 = bias + pos*W5p, 2 = bias + view*cWv
template<int K, int N, int INIT>
__device__ __forceinline__ void layerF(char* L, int biasOff, int wOff,
                                       int pg, int cg, int lane) {
  const float* P = (const float*)(L + LDS_PRM);
  const int col = lane & 15, kg = lane >> 4;
  constexpr int nCT = (N == 128) ? 4 : 2;
  f32x4 acc[4][nCT];
#pragma unroll
  for (int ptt = 0; ptt < 4; ++ptt)
#pragma unroll
    for (int ct = 0; ct < nCT; ++ct) {
      const int ch = (cg * nCT + ct) * 16 + col;
      const float b = P[biasOff + ch];
      f32x4 a;
#pragma unroll
      for (int r = 0; r < 4; ++r) {
        float v = b;
        if (INIT != 0) {
          const int pt = pg * 64 + ptt * 16 + kg * 4 + r;
          if (INIT == 1) {
            const float* pp = (const float*)(L + LDS_POS) + pt * 3;
            v += pp[0] * P[640 + ch] + pp[1] * P[768 + ch] + pp[2] * P[896 + ch];
          } else {
            const float* vv = (const float*)(L + LDS_VIEW) + (pt >> 7) * 3;
            v += vv[0] * P[1856 + ch] + vv[1] * P[1920 + ch] + vv[2] * P[1984 + ch];
          }
        }
        a[r] = v;
      }
      acc[ptt][ct] = a;
    }
#pragma unroll
  for (int ks = 0; ks < K / 32; ++ks) {
    const int kb = ks * 32 + kg * 8;
    f16x8 afr[4];
#pragma unroll
    for (int ptt = 0; ptt < 4; ++ptt) {
      const int row = pg * 64 + ptt * 16 + col;
      afr[ptt] = *(const f16x8*)(L + LDS_ACT + row * 256 + swz(row, 2 * kb));
    }
#pragma unroll
    for (int ct = 0; ct < nCT; ++ct) {
      const int och = (cg * nCT + ct) * 16 + col;
      const f16x8 bf = *(const f16x8*)(L + wOff + och * (2 * K) + swz(och, 2 * kb));
#pragma unroll
      for (int ptt = 0; ptt < 4; ++ptt)
        acc[ptt][ct] = __builtin_amdgcn_mfma_f32_16x16x32_f16(afr[ptt], bf,
                                                              acc[ptt][ct], 0, 0, 0);
    }
  }
  __syncthreads();  // all A/B reads done across block -> in-place write is safe
#pragma unroll
  for (int ptt = 0; ptt < 4; ++ptt)
#pragma unroll
    for (int ct = 0; ct < nCT; ++ct)
#pragma unroll
      for (int r = 0; r < 4; ++r) {
        const int pt = pg * 64 + ptt * 16 + kg * 4 + r;
        const int ch = (cg * nCT + ct) * 16 + col;
        const float v = fmaxf(acc[ptt][ct][r], 0.0f);
        *(f16*)(L + LDS_ACT + pt * 256 + swz(pt, 2 * ch)) = (f16)v;
      }
}

__global__ __launch_bounds__(512, 2) void nerf_main(
    const float* __restrict__ pos, const float* __restrict__ view,
    const char* __restrict__ ws, float* __restrict__ out) {
  __shared__ __align__(16) char L[LDS_SIZE];
  const int t = threadIdx.x, lane = t & 63, w = t >> 6;
  const int pg = w >> 1, cg = w & 1;
  const int base = blockIdx.x * 256;   // 256 points per block
  const float* P = (const float*)(L + LDS_PRM);

  // stage params / pos / view; prefetch W(0), W(1)
  for (int i = t; i < 2560; i += 512)
    ((float*)(L + LDS_PRM))[i] = ((const float*)(ws + WS_PARAMS))[i];
  for (int i = t; i < 768; i += 512)
    ((float*)(L + LDS_POS))[i] = pos[base * 3 + i];
  if (t < 6) ((float*)(L + LDS_VIEW))[t] = view[(base >> 7) * 3 + t];
  stage(ws + 0,     L + LDS_W0, 32768, t);
  stage(ws + 32768, L + LDS_W1, 32768, t);
  __syncthreads();

  // ---- L0 (K=3, pure VALU): h0 = relu(pos @ W0p + b0f) ----
  {
    const int pt = t >> 1, half = t & 1;
    const float* pp = (const float*)(L + LDS_POS) + pt * 3;
    const float p0 = pp[0], p1 = pp[1], p2 = pp[2];
#pragma unroll
    for (int c8 = 0; c8 < 8; ++c8) {
      f16x8 hv;
#pragma unroll
      for (int e = 0; e < 8; ++e) {
        const int ch = half * 64 + c8 * 8 + e;
        const float v = P[ch] + p0 * P[128 + ch] + p1 * P[256 + ch] + p2 * P[384 + ch];
        hv[e] = (f16)fmaxf(v, 0.0f);
      }
      const int kb = half * 64 + c8 * 8;
      *(f16x8*)(L + LDS_ACT + pt * 256 + swz(pt, 2 * kb)) = hv;
    }
  }
  __syncthreads();

  // ---- MFMA layers; layer i uses Wbuf[i&1]; stage(i+2) into just-freed buf ----
  layerF<128,128,0>(L, 1024, LDS_W0, pg, cg, lane);                 // L1
  stage(ws +  65536, L + LDS_W0, 32768, t); __syncthreads();
  layerF<128,128,0>(L, 1152, LDS_W1, pg, cg, lane);                 // L2
  stage(ws +  98304, L + LDS_W1, 32768, t); __syncthreads();
  layerF<128,128,0>(L, 1280, LDS_W0, pg, cg, lane);                 // L3
  stage(ws + 131072, L + LDS_W0, 32768, t); __syncthreads();
  layerF<128,128,0>(L, 1408, LDS_W1, pg, cg, lane);                 // L4
  stage(ws + 163840, L + LDS_W1, 32768, t); __syncthreads();
  layerF<128,128,1>(L,  512, LDS_W0, pg, cg, lane);                 // L5 (skip)
  stage(ws + 196608, L + LDS_W0, 32768, t); __syncthreads();
  layerF<128,128,0>(L, 1536, LDS_W1, pg, cg, lane);                 // L6
  stage(ws + 229376, L + LDS_W1, 16384, t); __syncthreads();
  layerF<128,128,0>(L, 1664, LDS_W0, pg, cg, lane);                 // L7
  stage(ws + 245760, L + LDS_W0,  8192, t); __syncthreads();

  // ---- sigma = h7 @ sW + sb (h7 now in act) ----
  if (cg == 0) {
    const int pt = pg * 64 + lane;
    float s = P[2304];
#pragma unroll
    for (int i8 = 0; i8 < 16; ++i8) {
      const f16x8 h = *(const f16x8*)(L + LDS_ACT + pt * 256 + swz(pt, 16 * i8));
#pragma unroll
      for (int e = 0; e < 8; ++e) s += (float)h[e] * P[2176 + i8 * 8 + e];
    }
    ((float*)(L + LDS_SIG))[pt] = s;
  }

  layerF<128,64,2>(L, 1792, LDS_W1, pg, cg, lane);                  // C0
  stage(ws + 253952, L + LDS_W1, 8192, t); __syncthreads();
  layerF<64,64,0>(L, 2048, LDS_W0, pg, cg, lane); __syncthreads();  // C1
  layerF<64,64,0>(L, 2112, LDS_W1, pg, cg, lane); __syncthreads();  // C2

  // ---- rgb = hC2 @ rW + rb; pack float4 output ----
  if (cg == 0) {
    const int pt = pg * 64 + lane;
    float a0 = P[2497], a1 = P[2498], a2 = P[2499];
#pragma unroll
    for (int i8 = 0; i8 < 8; ++i8) {
      const f16x8 h = *(const f16x8*)(L + LDS_ACT + pt * 256 + swz(pt, 16 * i8));
#pragma unroll
      for (int e = 0; e < 8; ++e) {
        const float hv = (float)h[e];
        const int k = i8 * 8 + e;
        a0 += hv * P[2305 + k * 3 + 0];
        a1 += hv * P[2305 + k * 3 + 1];
        a2 += hv * P[2305 + k * 3 + 2];
      }
    }
    float4 o;
    o.x = a0; o.y = a1; o.z = a2;
    o.w = ((const float*)(L + LDS_SIG))[pt];
    *(float4*)(out + (base + pt) * 4) = o;
  }
}

extern "C" void kernel_launch(void* const* d_in, const int* in_sizes, int n_in,
                              void* d_out, int out_size, void* d_ws, size_t ws_size,
                              hipStream_t stream) {
  Ptrs ptrs;
  for (int i = 0; i < 29; ++i) ptrs.p[i] = (const float*)d_in[i];
  char* ws = (char*)d_ws;
  nerf_prep<<<513, 256, 0, stream>>>(ptrs, ws);
  nerf_main<<<1024, 512, 0, stream>>>((const float*)d_in[0], (const float*)d_in[2],
                                      ws, (float*)d_out);
}

// Round 4
// 127.894 us; speedup vs baseline: 1.1400x; 1.1400x over previous
//
#include <hip/hip_runtime.h>

typedef _Float16 f16;
typedef _Float16 f16x8 __attribute__((ext_vector_type(8)));
typedef _Float16 f16x4 __attribute__((ext_vector_type(4)));
typedef float f32x4 __attribute__((ext_vector_type(4)));

// ---------------- d_ws layout ----------------
// [0, 262144)        : f16 weight images, transposed [out_ch][in_ch], pre-swizzled
//   img i in 0..6  (L1..L7h, 128x128) at i*32768
//   img 7 (C0h 64x128) at 229376 (16384 B)
//   img 8 (C1 64x64)   at 245760 (8192 B)
//   img 9 (C2 64x64)   at 253952 (8192 B)
// [262144, +10240)   : fp32 params block (folded biases etc.)  — R1 layout:
//   0 b0f[128] | 128 W0p[3][128] | 512 b5f[128] | 640 W5p[3][128]
//   1024 db1 1152 db2 1280 db3 1408 db4 1536 db6 1664 db7 (x128)
//   1792 cb0[64] | 1856 cWv[3][64] | 2048 cb1[64] | 2112 cb2[64]
//   2176 sW[128] | 2304 sb | 2305 rW[64][3] | 2497 rb[3]
#define WS_PARAMS 262144

// ---------------- LDS layout (bytes) ----------------
#define LDS_ACT   0
#define LDS_W0    65536
#define LDS_W1    98304
#define LDS_PRM   131072
#define LDS_POS   141312
#define LDS_VIEW  144384
#define LDS_SIG   144408
#define LDS_SIZE  145440

__device__ __forceinline__ int swz(int row, int byteInRow) {
  return byteInRow ^ ((row & 7) << 4);
}

struct Ptrs { const float* p[29]; };

// ---------------------------------------------------------------------------
// Prepass: fold cond into biases, convert/transpose/pre-swizzle weights to f16
// (verbatim from the round-1 PASSING kernel)
// ---------------------------------------------------------------------------
__global__ void nerf_prep(Ptrs ptrs, char* __restrict__ ws) {
  const int t = threadIdx.x;
  if (blockIdx.x == 0) {
    float* P = (float*)(ws + WS_PARAMS);
    const float* cond = ptrs.p[1];
    const float* dW0 = ptrs.p[3];  const float* db0 = ptrs.p[4];
    const float* dW5 = ptrs.p[13]; const float* db5 = ptrs.p[14];
    if (t < 128) {
      float a0 = db0[t], a5 = db5[t];
      for (int k = 0; k < 64; ++k) {
        const float c = cond[k];
        a0 += c * dW0[(3 + k) * 128 + t];
        a5 += c * dW5[(3 + k) * 128 + t];
      }
      P[t] = a0;          // b0f
      P[512 + t] = a5;    // b5f
      for (int k = 0; k < 3; ++k) {
        P[128 + k * 128 + t] = dW0[k * 128 + t];   // W0p
        P[640 + k * 128 + t] = dW5[k * 128 + t];   // W5p
      }
      P[1024 + t] = ptrs.p[6][t];    // db1
      P[1152 + t] = ptrs.p[8][t];    // db2
      P[1280 + t] = ptrs.p[10][t];   // db3
      P[1408 + t] = ptrs.p[12][t];   // db4
      P[1536 + t] = ptrs.p[16][t];   // db6
      P[1664 + t] = ptrs.p[18][t];   // db7
      P[2176 + t] = ptrs.p[19][t];   // sW
    }
    if (t < 64) {
      P[1792 + t] = ptrs.p[22][t];   // cb0
      for (int k = 0; k < 3; ++k)    // cWv = cW0 rows 128..130
        P[1856 + k * 64 + t] = ptrs.p[21][(128 + k) * 64 + t];
      P[2048 + t] = ptrs.p[24][t];   // cb1
      P[2112 + t] = ptrs.p[26][t];   // cb2
    }
    if (t < 192) P[2305 + t] = ptrs.p[27][t];  // rW [64][3]
    if (t == 0) {
      P[2304] = ptrs.p[20][0];                 // sb
      P[2497] = ptrs.p[28][0];
      P[2498] = ptrs.p[28][1];
      P[2499] = ptrs.p[28][2];                 // rb
    }
    return;
  }
  // weight conversion: 131072 f16 elements across blocks 1..512
  const int w = (blockIdx.x - 1) * 256 + t;
  float v; int dst;
  if (w < 114688) {                       // L1..L7: 7 images of 128x128
    const int img = w >> 14, r = w & 16383, n = r >> 7, k = r & 127;
    const int srow = k + (img == 4 ? 67 : 0);     // L5h uses dW5 rows 67..194
    v = ptrs.p[5 + 2 * img][srow * 128 + n];
    dst = img * 32768 + n * 256 + swz(n, 2 * k);
  } else if (w < 122880) {                // C0h: cW0 rows 0..127, N=64
    const int r = w - 114688, n = r >> 7, k = r & 127;
    v = ptrs.p[21][k * 64 + n];
    dst = 229376 + n * 256 + swz(n, 2 * k);
  } else if (w < 126976) {                // C1 64x64
    const int r = w - 122880, n = r >> 6, k = r & 63;
    v = ptrs.p[23][k * 64 + n];
    dst = 245760 + n * 128 + swz(n, 2 * k);
  } else {                                // C2 64x64
    const int r = w - 126976, n = r >> 6, k = r & 63;
    v = ptrs.p[25][k * 64 + n];
    dst = 253952 + n * 128 + swz(n, 2 * k);
  }
  *(f16*)(ws + dst) = (f16)v;
}

// ---------------------------------------------------------------------------
// Main fused kernel
// ---------------------------------------------------------------------------
__device__ __forceinline__ void stage(const char* __restrict__ g, char* d,
                                      int bytes, int t) {
  for (int off = t * 16; off < bytes; off += 8192)
    *(int4*)(d + off) = *(const int4*)(g + off);
}

// Orientation-swapped vs round-1: A = weight fragments (rows = out-channels),
// B = activation fragments (cols = points). C: row = och (kg*4+r), col = pt.
// Epilogue: one packed f16x4 store per (pt-tile, och-tile) — 16 b64 stores/lane
// instead of 64 scalar b16 stores (the round-1 bank-conflict hotspot).
// INIT: 0 = bias only, 1 = bias + pos*W5p, 2 = bias + view*cWv
template<int K, int N, int INIT>
__device__ __forceinline__ void layerF(char* L, int biasOff, int wOff,
                                       int pg, int cg, int lane) {
  const float* P = (const float*)(L + LDS_PRM);
  const int col = lane & 15, kg = lane >> 4;
  constexpr int nCT = (N == 128) ? 4 : 2;
  const int ochQ = kg * 4;
  f32x4 acc[4][nCT];
#pragma unroll
  for (int ct = 0; ct < nCT; ++ct) {
    const int ochB = (cg * nCT + ct) * 16 + ochQ;
    const f32x4 bq = *(const f32x4*)(P + biasOff + ochB);
    f32x4 w0q, w1q, w2q;
    if (INIT == 1) {
      w0q = *(const f32x4*)(P + 640 + ochB);
      w1q = *(const f32x4*)(P + 768 + ochB);
      w2q = *(const f32x4*)(P + 896 + ochB);
    } else if (INIT == 2) {
      w0q = *(const f32x4*)(P + 1856 + ochB);
      w1q = *(const f32x4*)(P + 1920 + ochB);
      w2q = *(const f32x4*)(P + 1984 + ochB);
    }
#pragma unroll
    for (int ptc = 0; ptc < 4; ++ptc) {
      f32x4 v = bq;
      if (INIT != 0) {
        const int pt = pg * 64 + ptc * 16 + col;
        float p0, p1, p2;
        if (INIT == 1) {
          const float* pp = (const float*)(L + LDS_POS) + pt * 3;
          p0 = pp[0]; p1 = pp[1]; p2 = pp[2];
        } else {
          const float* vv = (const float*)(L + LDS_VIEW) + (pt >> 7) * 3;
          p0 = vv[0]; p1 = vv[1]; p2 = vv[2];
        }
        v += p0 * w0q + p1 * w1q + p2 * w2q;
      }
      acc[ptc][ct] = v;
    }
  }
#pragma unroll
  for (int ks = 0; ks < K / 32; ++ks) {
    f16x8 afr[nCT];
#pragma unroll
    for (int ct = 0; ct < nCT; ++ct) {
      const int och = (cg * nCT + ct) * 16 + col;
      afr[ct] = *(const f16x8*)(L + wOff + och * (2 * K) + swz(och, ks * 64 + kg * 16));
    }
#pragma unroll
    for (int ptc = 0; ptc < 4; ++ptc) {
      const int pt = pg * 64 + ptc * 16 + col;
      const f16x8 bfr = *(const f16x8*)(L + LDS_ACT + pt * 256 + swz(pt, ks * 64 + kg * 16));
#pragma unroll
      for (int ct = 0; ct < nCT; ++ct)
        acc[ptc][ct] = __builtin_amdgcn_mfma_f32_16x16x32_f16(afr[ct], bfr,
                                                              acc[ptc][ct], 0, 0, 0);
    }
  }
  __syncthreads();  // all A/B reads done across block -> in-place write is safe
#pragma unroll
  for (int ptc = 0; ptc < 4; ++ptc) {
    const int pt = pg * 64 + ptc * 16 + col;
#pragma unroll
    for (int ct = 0; ct < nCT; ++ct) {
      const int ochB = (cg * nCT + ct) * 16 + ochQ;
      const f32x4 v = acc[ptc][ct];
      f16x4 h;
#pragma unroll
      for (int e = 0; e < 4; ++e) h[e] = (f16)fmaxf(v[e], 0.f);
      *(f16x4*)(L + LDS_ACT + pt * 256 + swz(pt, ochB * 2)) = h;
    }
  }
}

__global__ __launch_bounds__(512, 2) void nerf_main(
    const float* __restrict__ pos, const float* __restrict__ view,
    const char* __restrict__ ws, float* __restrict__ out) {
  __shared__ __align__(16) char L[LDS_SIZE];
  const int t = threadIdx.x, lane = t & 63, w = t >> 6;
  const int pg = w >> 1, cg = w & 1;
  const int base = blockIdx.x * 256;   // 256 points per block
  const float* P = (const float*)(L + LDS_PRM);

  // stage params / pos / view; prefetch W(0), W(1)
  for (int i = t; i < 2560; i += 512)
    ((float*)(L + LDS_PRM))[i] = ((const float*)(ws + WS_PARAMS))[i];
  for (int i = t; i < 768; i += 512)
    ((float*)(L + LDS_POS))[i] = pos[base * 3 + i];
  if (t < 6) ((float*)(L + LDS_VIEW))[t] = view[(base >> 7) * 3 + t];
  stage(ws + 0,     L + LDS_W0, 32768, t);
  stage(ws + 32768, L + LDS_W1, 32768, t);
  __syncthreads();

  // ---- L0 (K=3, pure VALU): h0 = relu(pos @ W0p + b0f) ----
  {
    const int pt = t >> 1, half = t & 1;
    const float* pp = (const float*)(L + LDS_POS) + pt * 3;
    const float p0 = pp[0], p1 = pp[1], p2 = pp[2];
#pragma unroll
    for (int c8 = 0; c8 < 8; ++c8) {
      f16x8 hv;
#pragma unroll
      for (int e = 0; e < 8; ++e) {
        const int ch = half * 64 + c8 * 8 + e;
        const float v = P[ch] + p0 * P[128 + ch] + p1 * P[256 + ch] + p2 * P[384 + ch];
        hv[e] = (f16)fmaxf(v, 0.0f);
      }
      const int kb = half * 64 + c8 * 8;
      *(f16x8*)(L + LDS_ACT + pt * 256 + swz(pt, 2 * kb)) = hv;
    }
  }
  __syncthreads();

  // ---- MFMA layers; layer i uses Wbuf[i&1]; stage(i+2) into just-freed buf ----
  layerF<128,128,0>(L, 1024, LDS_W0, pg, cg, lane);                 // L1
  stage(ws +  65536, L + LDS_W0, 32768, t); __syncthreads();
  layerF<128,128,0>(L, 1152, LDS_W1, pg, cg, lane);                 // L2
  stage(ws +  98304, L + LDS_W1, 32768, t); __syncthreads();
  layerF<128,128,0>(L, 1280, LDS_W0, pg, cg, lane);                 // L3
  stage(ws + 131072, L + LDS_W0, 32768, t); __syncthreads();
  layerF<128,128,0>(L, 1408, LDS_W1, pg, cg, lane);                 // L4
  stage(ws + 163840, L + LDS_W1, 32768, t); __syncthreads();
  layerF<128,128,1>(L,  512, LDS_W0, pg, cg, lane);                 // L5 (skip)
  stage(ws + 196608, L + LDS_W0, 32768, t); __syncthreads();
  layerF<128,128,0>(L, 1536, LDS_W1, pg, cg, lane);                 // L6
  stage(ws + 229376, L + LDS_W1, 16384, t); __syncthreads();
  layerF<128,128,0>(L, 1664, LDS_W0, pg, cg, lane);                 // L7
  stage(ws + 245760, L + LDS_W0,  8192, t); __syncthreads();

  // ---- sigma = h7 @ sW + sb (h7 now in act) ----
  if (cg == 0) {
    const int pt = pg * 64 + lane;
    float s = P[2304];
#pragma unroll
    for (int i8 = 0; i8 < 16; ++i8) {
      const f16x8 h = *(const f16x8*)(L + LDS_ACT + pt * 256 + swz(pt, 16 * i8));
#pragma unroll
      for (int e = 0; e < 8; ++e) s += (float)h[e] * P[2176 + i8 * 8 + e];
    }
    ((float*)(L + LDS_SIG))[pt] = s;
  }

  layerF<128,64,2>(L, 1792, LDS_W1, pg, cg, lane);                  // C0
  stage(ws + 253952, L + LDS_W1, 8192, t); __syncthreads();
  layerF<64,64,0>(L, 2048, LDS_W0, pg, cg, lane); __syncthreads();  // C1
  layerF<64,64,0>(L, 2112, LDS_W1, pg, cg, lane); __syncthreads();  // C2

  // ---- rgb = hC2 @ rW + rb; pack float4 output ----
  if (cg == 0) {
    const int pt = pg * 64 + lane;
    float a0 = P[2497], a1 = P[2498], a2 = P[2499];
#pragma unroll
    for (int i8 = 0; i8 < 8; ++i8) {
      const f16x8 h = *(const f16x8*)(L + LDS_ACT + pt * 256 + swz(pt, 16 * i8));
#pragma unroll
      for (int e = 0; e < 8; ++e) {
        const float hv = (float)h[e];
        const int k = i8 * 8 + e;
        a0 += hv * P[2305 + k * 3 + 0];
        a1 += hv * P[2305 + k * 3 + 1];
        a2 += hv * P[2305 + k * 3 + 2];
      }
    }
    float4 o;
    o.x = a0; o.y = a1; o.z = a2;
    o.w = ((const float*)(L + LDS_SIG))[pt];
    *(float4*)(out + (base + pt) * 4) = o;
  }
}

extern "C" void kernel_launch(void* const* d_in, const int* in_sizes, int n_in,
                              void* d_out, int out_size, void* d_ws, size_t ws_size,
                              hipStream_t stream) {
  Ptrs ptrs;
  for (int i = 0; i < 29; ++i) ptrs.p[i] = (const float*)d_in[i];
  char* ws = (char*)d_ws;
  nerf_prep<<<513, 256, 0, stream>>>(ptrs, ws);
  nerf_main<<<1024, 512, 0, stream>>>((const float*)d_in[0], (const float*)d_in[2],
                                      ws, (float*)d_out);
}

// Round 6
// 111.635 us; speedup vs baseline: 1.3060x; 1.1456x over previous
//
#include <hip/hip_runtime.h>

typedef _Float16 f16;
typedef _Float16 f16x8 __attribute__((ext_vector_type(8)));
typedef _Float16 f16x4 __attribute__((ext_vector_type(4)));
typedef float f32x4 __attribute__((ext_vector_type(4)));

// ---------------- d_ws layout ----------------
// [0, 262144)        : f16 weight images, transposed [out_ch][in_ch], pre-swizzled
//   img i in 0..6  (L1..L7h, 128x128) at i*32768
//   img 7 (C0h 64x128) at 229376 (16384 B)
//   img 8 (C1 64x64)   at 245760 (8192 B)
//   img 9 (C2 64x64)   at 253952 (8192 B)
// [262144, +10240)   : fp32 params block:
//   0 b0f[128] | 128 W0p[3][128] | 512 b5f[128] | 640 W5p[3][128]
//   1024 db1 1152 db2 1280 db3 1408 db4 1536 db6 1664 db7 (x128)
//   1792 cb0[64] | 1856 cWv[3][64] | 2048 cb1[64] | 2112 cb2[64]
//   2176 sW[128] | 2304 sb | 2305 rW[64][3] | 2497 rb[3]
#define WS_PARAMS 262144

// ---------------- LDS layout (bytes) ----------------
#define LDS_ACT   0
#define LDS_W0    65536
#define LDS_W1    98304
#define LDS_PRM   131072
#define LDS_POS   141312
#define LDS_VIEW  144384
#define LDS_SIG   144408
#define LDS_SIZE  145440

__device__ __forceinline__ int swz(int row, int byteInRow) {
  return byteInRow ^ ((row & 7) << 4);
}

struct Ptrs { const float* p[29]; };

// ---------------------------------------------------------------------------
// Prepass (verbatim from the validated R4 kernel)
// ---------------------------------------------------------------------------
__global__ void nerf_prep(Ptrs ptrs, char* __restrict__ ws) {
  const int t = threadIdx.x;
  if (blockIdx.x == 0) {
    float* P = (float*)(ws + WS_PARAMS);
    const float* cond = ptrs.p[1];
    const float* dW0 = ptrs.p[3];  const float* db0 = ptrs.p[4];
    const float* dW5 = ptrs.p[13]; const float* db5 = ptrs.p[14];
    if (t < 128) {
      float a0 = db0[t], a5 = db5[t];
      for (int k = 0; k < 64; ++k) {
        const float c = cond[k];
        a0 += c * dW0[(3 + k) * 128 + t];
        a5 += c * dW5[(3 + k) * 128 + t];
      }
      P[t] = a0;          // b0f
      P[512 + t] = a5;    // b5f
      for (int k = 0; k < 3; ++k) {
        P[128 + k * 128 + t] = dW0[k * 128 + t];   // W0p
        P[640 + k * 128 + t] = dW5[k * 128 + t];   // W5p
      }
      P[1024 + t] = ptrs.p[6][t];    // db1
      P[1152 + t] = ptrs.p[8][t];    // db2
      P[1280 + t] = ptrs.p[10][t];   // db3
      P[1408 + t] = ptrs.p[12][t];   // db4
      P[1536 + t] = ptrs.p[16][t];   // db6
      P[1664 + t] = ptrs.p[18][t];   // db7
      P[2176 + t] = ptrs.p[19][t];   // sW
    }
    if (t < 64) {
      P[1792 + t] = ptrs.p[22][t];   // cb0
      for (int k = 0; k < 3; ++k)    // cWv = cW0 rows 128..130
        P[1856 + k * 64 + t] = ptrs.p[21][(128 + k) * 64 + t];
      P[2048 + t] = ptrs.p[24][t];   // cb1
      P[2112 + t] = ptrs.p[26][t];   // cb2
    }
    if (t < 192) P[2305 + t] = ptrs.p[27][t];  // rW [64][3]
    if (t == 0) {
      P[2304] = ptrs.p[20][0];                 // sb
      P[2497] = ptrs.p[28][0];
      P[2498] = ptrs.p[28][1];
      P[2499] = ptrs.p[28][2];                 // rb
    }
    return;
  }
  // weight conversion: 131072 f16 elements across blocks 1..512
  const int w = (blockIdx.x - 1) * 256 + t;
  float v; int dst;
  if (w < 114688) {                       // L1..L7: 7 images of 128x128
    const int img = w >> 14, r = w & 16383, n = r >> 7, k = r & 127;
    const int srow = k + (img == 4 ? 67 : 0);     // L5h uses dW5 rows 67..194
    v = ptrs.p[5 + 2 * img][srow * 128 + n];
    dst = img * 32768 + n * 256 + swz(n, 2 * k);
  } else if (w < 122880) {                // C0h: cW0 rows 0..127, N=64
    const int r = w - 114688, n = r >> 7, k = r & 127;
    v = ptrs.p[21][k * 64 + n];
    dst = 229376 + n * 256 + swz(n, 2 * k);
  } else if (w < 126976) {                // C1 64x64
    const int r = w - 122880, n = r >> 6, k = r & 63;
    v = ptrs.p[23][k * 64 + n];
    dst = 245760 + n * 128 + swz(n, 2 * k);
  } else {                                // C2 64x64
    const int r = w - 126976, n = r >> 6, k = r & 63;
    v = ptrs.p[25][k * 64 + n];
    dst = 253952 + n * 128 + swz(n, 2 * k);
  }
  *(f16*)(ws + dst) = (f16)v;
}

// ---------------------------------------------------------------------------
// Async global->LDS DMA staging (no VGPR round-trip). LDS dest is
// wave-uniform base + lane*16 (linear), as required by global_load_lds.
// Issued at layer START targeting the DEAD buffer (read by layer i-1, whose
// readers all passed that layer's internal barrier); drained by the
// vmcnt(0) the compiler emits before the next __syncthreads.
// ---------------------------------------------------------------------------
__device__ __forceinline__ void dmaW(char* dst, const char* __restrict__ g,
                                     int bytes, int t) {
  for (int off = t * 16; off < bytes; off += 8192)
    __builtin_amdgcn_global_load_lds(
        (const __attribute__((address_space(1))) unsigned int*)(g + off),
        (__attribute__((address_space(3))) unsigned int*)(dst + off), 16, 0, 0);
}

// A = weight fragments (rows = out-channels), B = activation fragments
// (cols = points). C: row = och (kg*4+r), col = pt. Epilogue: packed f16x4.
// INIT: 0 = bias only, 1 = bias + pos*W5p, 2 = bias + view*cWv
template<int K, int N, int INIT>
__device__ __forceinline__ void layerF(char* L, int biasOff, int wOff,
                                       int pg, int cg, int lane) {
  const float* P = (const float*)(L + LDS_PRM);
  const int col = lane & 15, kg = lane >> 4;
  constexpr int nCT = (N == 128) ? 4 : 2;
  const int ochQ = kg * 4;
  f32x4 acc[4][nCT];
#pragma unroll
  for (int ct = 0; ct < nCT; ++ct) {
    const int ochB = (cg * nCT + ct) * 16 + ochQ;
    const f32x4 bq = *(const f32x4*)(P + biasOff + ochB);
    f32x4 w0q, w1q, w2q;
    if (INIT == 1) {
      w0q = *(const f32x4*)(P + 640 + ochB);
      w1q = *(const f32x4*)(P + 768 + ochB);
      w2q = *(const f32x4*)(P + 896 + ochB);
    } else if (INIT == 2) {
      w0q = *(const f32x4*)(P + 1856 + ochB);
      w1q = *(const f32x4*)(P + 1920 + ochB);
      w2q = *(const f32x4*)(P + 1984 + ochB);
    }
#pragma unroll
    for (int ptc = 0; ptc < 4; ++ptc) {
      f32x4 v = bq;
      if (INIT != 0) {
        const int pt = pg * 64 + ptc * 16 + col;
        float p0, p1, p2;
        if (INIT == 1) {
          const float* pp = (const float*)(L + LDS_POS) + pt * 3;
          p0 = pp[0]; p1 = pp[1]; p2 = pp[2];
        } else {
          const float* vv = (const float*)(L + LDS_VIEW) + (pt >> 7) * 3;
          p0 = vv[0]; p1 = vv[1]; p2 = vv[2];
        }
        v += p0 * w0q + p1 * w1q + p2 * w2q;
      }
      acc[ptc][ct] = v;
    }
  }
  __builtin_amdgcn_s_setprio(1);
#pragma unroll
  for (int ks = 0; ks < K / 32; ++ks) {
    f16x8 afr[nCT];
#pragma unroll
    for (int ct = 0; ct < nCT; ++ct) {
      const int och = (cg * nCT + ct) * 16 + col;
      afr[ct] = *(const f16x8*)(L + wOff + och * (2 * K) + swz(och, ks * 64 + kg * 16));
    }
#pragma unroll
    for (int ptc = 0; ptc < 4; ++ptc) {
      const int pt = pg * 64 + ptc * 16 + col;
      const f16x8 bfr = *(const f16x8*)(L + LDS_ACT + pt * 256 + swz(pt, ks * 64 + kg * 16));
#pragma unroll
      for (int ct = 0; ct < nCT; ++ct)
        acc[ptc][ct] = __builtin_amdgcn_mfma_f32_16x16x32_f16(afr[ct], bfr,
                                                              acc[ptc][ct], 0, 0, 0);
    }
  }
  __builtin_amdgcn_s_setprio(0);
  __syncthreads();  // all act/W reads done block-wide -> in-place act write safe
#pragma unroll
  for (int ptc = 0; ptc < 4; ++ptc) {
    const int pt = pg * 64 + ptc * 16 + col;
#pragma unroll
    for (int ct = 0; ct < nCT; ++ct) {
      const int ochB = (cg * nCT + ct) * 16 + ochQ;
      const f32x4 v = acc[ptc][ct];
      f16x4 h;
#pragma unroll
      for (int e = 0; e < 4; ++e) h[e] = (f16)fmaxf(v[e], 0.f);
      *(f16x4*)(L + LDS_ACT + pt * 256 + swz(pt, ochB * 2)) = h;
    }
  }
}

__global__ __launch_bounds__(512, 2) void nerf_main(
    const float* __restrict__ pos, const float* __restrict__ view,
    const char* __restrict__ ws, float* __restrict__ out) {
  __shared__ __align__(16) char L[LDS_SIZE];
  const int t = threadIdx.x, lane = t & 63, w = t >> 6;
  const int pg = w >> 1, cg = w & 1;
  const int base = blockIdx.x * 256;   // 256 points per block
  const float* P = (const float*)(L + LDS_PRM);

  // stage params / pos / view (plain LDS writes); DMA W(L1) -> buf0
  for (int i = t; i < 2560; i += 512)
    ((float*)(L + LDS_PRM))[i] = ((const float*)(ws + WS_PARAMS))[i];
  for (int i = t; i < 768; i += 512)
    ((float*)(L + LDS_POS))[i] = pos[base * 3 + i];
  if (t < 6) ((float*)(L + LDS_VIEW))[t] = view[(base >> 7) * 3 + t];
  dmaW(L + LDS_W0, ws + 0, 32768, t);
  __syncthreads();

  // ---- L0 (K=3, pure VALU): h0 = relu(pos @ W0p + b0f) ----
  {
    const int pt = t >> 1, half = t & 1;
    const float* pp = (const float*)(L + LDS_POS) + pt * 3;
    const float p0 = pp[0], p1 = pp[1], p2 = pp[2];
#pragma unroll
    for (int c8 = 0; c8 < 8; ++c8) {
      f16x8 hv;
#pragma unroll
      for (int e = 0; e < 8; ++e) {
        const int ch = half * 64 + c8 * 8 + e;
        const float v = P[ch] + p0 * P[128 + ch] + p1 * P[256 + ch] + p2 * P[384 + ch];
        hv[e] = (f16)fmaxf(v, 0.0f);
      }
      const int kb = half * 64 + c8 * 8;
      *(f16x8*)(L + LDS_ACT + pt * 256 + swz(pt, 2 * kb)) = hv;
    }
  }
  __syncthreads();

  // ---- MFMA layers. At layer-i start: DMA W(i+1) into the dead buffer
  // (the one layer i-1 read). Layer i reads the other buffer. The caller
  // barrier after layerF drains both the DMA and the epilogue writes. ----
  dmaW(L + LDS_W1, ws +  32768, 32768, t);
  layerF<128,128,0>(L, 1024, LDS_W0, pg, cg, lane);  __syncthreads();  // L1
  dmaW(L + LDS_W0, ws +  65536, 32768, t);
  layerF<128,128,0>(L, 1152, LDS_W1, pg, cg, lane);  __syncthreads();  // L2
  dmaW(L + LDS_W1, ws +  98304, 32768, t);
  layerF<128,128,0>(L, 1280, LDS_W0, pg, cg, lane);  __syncthreads();  // L3
  dmaW(L + LDS_W0, ws + 131072, 32768, t);
  layerF<128,128,0>(L, 1408, LDS_W1, pg, cg, lane);  __syncthreads();  // L4
  dmaW(L + LDS_W1, ws + 163840, 32768, t);
  layerF<128,128,1>(L,  512, LDS_W0, pg, cg, lane);  __syncthreads();  // L5 (skip)
  dmaW(L + LDS_W0, ws + 196608, 32768, t);
  layerF<128,128,0>(L, 1536, LDS_W1, pg, cg, lane);  __syncthreads();  // L6
  dmaW(L + LDS_W1, ws + 229376, 16384, t);
  layerF<128,128,0>(L, 1664, LDS_W0, pg, cg, lane);  __syncthreads();  // L7

  // ---- sigma = h7 @ sW + sb, all 512 threads (2 per point).
  // h7 stable until C0's internal barrier (all threads pass sigma first). ----
  dmaW(L + LDS_W0, ws + 245760, 8192, t);            // C1 weights -> buf0
  {
    const int pt2 = t >> 1, half = t & 1;
    float s = 0.f;
#pragma unroll
    for (int i8 = 0; i8 < 8; ++i8) {
      const f16x8 h = *(const f16x8*)(L + LDS_ACT + pt2 * 256 + swz(pt2, half * 128 + i8 * 16));
#pragma unroll
      for (int e = 0; e < 8; ++e) s += (float)h[e] * P[2176 + half * 64 + i8 * 8 + e];
    }
    s += __shfl_xor(s, 1);
    if (!half) ((float*)(L + LDS_SIG))[pt2] = s + P[2304];
  }

  layerF<128,64,2>(L, 1792, LDS_W1, pg, cg, lane);   __syncthreads();  // C0
  dmaW(L + LDS_W1, ws + 253952, 8192, t);            // C2 weights -> buf1
  layerF<64,64,0>(L, 2048, LDS_W0, pg, cg, lane);    __syncthreads();  // C1
  layerF<64,64,0>(L, 2112, LDS_W1, pg, cg, lane);    __syncthreads();  // C2

  // ---- rgb = hC2 @ rW + rb, all 512 threads (2 per point) ----
  {
    const int pt2 = t >> 1, half = t & 1;
    float a0 = 0.f, a1 = 0.f, a2 = 0.f;
#pragma unroll
    for (int i8 = 0; i8 < 4; ++i8) {
      const f16x8 h = *(const f16x8*)(L + LDS_ACT + pt2 * 256 + swz(pt2, half * 64 + i8 * 16));
#pragma unroll
      for (int e = 0; e < 8; ++e) {
        const float hv = (float)h[e];
        const int k = half * 32 + i8 * 8 + e;
        a0 += hv * P[2305 + k * 3 + 0];
        a1 += hv * P[2305 + k * 3 + 1];
        a2 += hv * P[2305 + k * 3 + 2];
      }
    }
    a0 += __shfl_xor(a0, 1);
    a1 += __shfl_xor(a1, 1);
    a2 += __shfl_xor(a2, 1);
    if (!half) {
      float4 o;
      o.x = a0 + P[2497]; o.y = a1 + P[2498]; o.z = a2 + P[2499];
      o.w = ((const float*)(L + LDS_SIG))[pt2];
      *(float4*)(out + (base + pt2) * 4) = o;
    }
  }
}

extern "C" void kernel_launch(void* const* d_in, const int* in_sizes, int n_in,
                              void* d_out, int out_size, void* d_ws, size_t ws_size,
                              hipStream_t stream) {
  Ptrs ptrs;
  for (int i = 0; i < 29; ++i) ptrs.p[i] = (const float*)d_in[i];
  char* ws = (char*)d_ws;
  nerf_prep<<<513, 256, 0, stream>>>(ptrs, ws);
  nerf_main<<<1024, 512, 0, stream>>>((const float*)d_in[0], (const float*)d_in[2],
                                      ws, (float*)d_out);
}